// Round 1
// baseline (589.253 us; speedup 1.0000x reference)
//
#include <hip/hip_runtime.h>

typedef unsigned short u16;
typedef __bf16 bf16x8 __attribute__((ext_vector_type(8)));
typedef float f32x4 __attribute__((ext_vector_type(4)));

typedef __attribute__((address_space(1))) void gvoid;
typedef __attribute__((address_space(3))) void lvoid;

__device__ __forceinline__ u16 f2bf(float f) {
  unsigned int u = __builtin_bit_cast(unsigned int, f);
  u += 0x7fffu + ((u >> 16) & 1u);
  return (u16)(u >> 16);
}

__device__ __forceinline__ void gl_lds16(const u16* g, u16* l) {
  // async global->LDS, 16B per lane; LDS dest = wave-uniform base + lane*16
  __builtin_amdgcn_global_load_lds((gvoid*)(g), (lvoid*)(l), 16, 0, 0);
}

// ---------------- W_eff[c][j] = sum_s rmsw[s*1024+c] * Wdyn[(s*1024+c)*24 + j] ---------
__global__ __launch_bounds__(256) void weff_kernel(const float* __restrict__ rmsw,
                                                   const float* __restrict__ Wdyn,
                                                   float* __restrict__ Weff) {
  int idx = blockIdx.x * 256 + threadIdx.x;  // 1024*24 = 24576 threads
  int c = idx / 24, j = idx - c * 24;
  float s = 0.f;
#pragma unroll
  for (int st = 0; st < 4; ++st) {
    int r = st * 1024 + c;
    s += rmsw[r] * Wdyn[(long)r * 24 + j];
  }
  Weff[idx] = s;
}

// ---------------- transpose fp32 (R x C) -> bf16 (C x R) --------------------------------
__global__ __launch_bounds__(256) void transpose_kernel(const float* __restrict__ src,
                                                        u16* __restrict__ dst,
                                                        int R, int C) {
  __shared__ float tile[32][33];
  int tx = threadIdx.x & 31, ty = threadIdx.x >> 5;  // 32 x 8
  long c0 = (long)blockIdx.x * 32, r0 = (long)blockIdx.y * 32;
#pragma unroll
  for (int k = 0; k < 4; ++k)
    tile[ty + 8 * k][tx] = src[(r0 + ty + 8 * k) * C + c0 + tx];
  __syncthreads();
#pragma unroll
  for (int k = 0; k < 4; ++k)
    dst[(c0 + ty + 8 * k) * R + r0 + tx] = f2bf(tile[tx][ty + 8 * k]);
}

// ---------------- per-token prep: rms, dynamic(24), gates, sinkhorn, preA ---------------
__global__ __launch_bounds__(256) void prep_tokens(
    const float* __restrict__ x, const float* __restrict__ Weff,
    const float* __restrict__ bias_pre, const float* __restrict__ bias_post,
    const float* __restrict__ bias_res, const float* __restrict__ a_pre,
    const float* __restrict__ a_post, const float* __restrict__ a_res,
    u16* __restrict__ preA, float* __restrict__ scal) {
  const int t = blockIdx.x;
  const int tid = threadIdx.x;
  const float4 xv = *(const float4*)(x + (long)t * 1024 + tid * 4);
  float ssq = xv.x * xv.x + xv.y * xv.y + xv.z * xv.z + xv.w * xv.w;
  float raw[24];
#pragma unroll
  for (int j = 0; j < 24; ++j) raw[j] = 0.f;
  const float xs[4] = {xv.x, xv.y, xv.z, xv.w};
  const float* wrow = Weff + (long)tid * 96;  // 4 rows of 24
#pragma unroll
  for (int cc = 0; cc < 4; ++cc) {
    const float4* wr = (const float4*)(wrow + cc * 24);
    const float xc = xs[cc];
#pragma unroll
    for (int q = 0; q < 6; ++q) {
      float4 w = wr[q];
      raw[q * 4 + 0] += xc * w.x;
      raw[q * 4 + 1] += xc * w.y;
      raw[q * 4 + 2] += xc * w.z;
      raw[q * 4 + 3] += xc * w.w;
    }
  }
  // wave64 butterfly reduce of 25 partials
#pragma unroll
  for (int m = 1; m < 64; m <<= 1) {
    ssq += __shfl_xor(ssq, m);
#pragma unroll
    for (int j = 0; j < 24; ++j) raw[j] += __shfl_xor(raw[j], m);
  }
  __shared__ float red[4][25];
  __shared__ float tot[25];
  const int lane = tid & 63, wv = tid >> 6;
  if (lane == 0) {
#pragma unroll
    for (int j = 0; j < 24; ++j) red[wv][j] = raw[j];
    red[wv][24] = ssq;
  }
  __syncthreads();
  if (tid < 25) tot[tid] = red[0][tid] + red[1][tid] + red[2][tid] + red[3][tid];
  __syncthreads();

  const float rms = sqrtf(tot[24] * (1.0f / 1024.0f) + 1e-8f);
  const float rinv = 1.0f / rms;

  // s_pre (every thread computes; identical)
  const float ap = a_pre[0];
  float s_pre = 0.f;
#pragma unroll
  for (int i = 0; i < 4; ++i)
    s_pre += 1.f / (1.f + expf(-(ap * tot[i] * rinv + bias_pre[i])));

  // preA = bf16(s_pre * x)
  unsigned int lo = (unsigned)f2bf(s_pre * xv.x) | ((unsigned)f2bf(s_pre * xv.y) << 16);
  unsigned int hi = (unsigned)f2bf(s_pre * xv.z) | ((unsigned)f2bf(s_pre * xv.w) << 16);
  *(uint2*)(preA + (long)t * 1024 + tid * 4) = make_uint2(lo, hi);

  // sinkhorn on lanes 0..15 of wave 0 (lane = i*4 + j)
  if (tid < 16) {
    const float ar = a_res[0];
    float Mv = expf(ar * tot[8 + tid] * rinv + bias_res[tid]);
#pragma unroll
    for (int it = 0; it < 20; ++it) {
      float cs = Mv + __shfl_xor(Mv, 4);
      cs += __shfl_xor(cs, 8);
      Mv = Mv / (cs + 1e-8f);   // col normalize (axis=-2)
      float rs = Mv + __shfl_xor(Mv, 1);
      rs += __shfl_xor(rs, 2);
      Mv = Mv / (rs + 1e-8f);   // row normalize (axis=-1)
    }
    float rs = Mv + __shfl_xor(Mv, 1);
    rs += __shfl_xor(rs, 2);
    if ((tid & 3) == 0) scal[(long)t * 8 + (tid >> 2)] = rs;  // r_i
  }
  if (tid < 4) {
    const float apo = a_post[0];
    float hp = 2.f / (1.f + expf(-(apo * tot[4 + tid] * rinv + bias_post[tid])));
    scal[(long)t * 8 + 4 + tid] = hp;  // H_post
  }
}

// ---------------- bf16 MFMA GEMM: C(MxN) = A(MxK, row-major) * Bt(NxK)^T ----------------
// BM=BN=128, BK=64, 256 threads (4 waves, 2x2), each wave 4x4 of 16x16x32 MFMA.
// LDS layout XOR-swizzled: elem (m, kc) at phys m*64 + ((kc ^ (m&7))*8)  [kc = k/8]
//  -> global_load_lds-compatible (contiguous lane order), conflict-free ds_read_b128,
//     coalesced 128B-per-8-lane global reads.
// EPI: 0 = gelu -> bf16 dst (ld N) | 1 = build merged (ld 4096) | 2 = +bias+x -> fp32
template <int EPI>
__global__ __launch_bounds__(256) void gemm_bf16(const u16* __restrict__ A,
                                                 const u16* __restrict__ Bt,
                                                 const int K, const int N,
                                                 const float* __restrict__ bias,
                                                 const float* __restrict__ X,
                                                 const float* __restrict__ scal,
                                                 void* __restrict__ dstv) {
  __shared__ __attribute__((aligned(16))) u16 As[128 * 64];
  __shared__ __attribute__((aligned(16))) u16 Bs[128 * 64];
  const int tid = threadIdx.x;
  const int lane = tid & 63;
  const int wave = tid >> 6;
  const int wm = wave >> 1, wn = wave & 1;
  const long bm = (long)blockIdx.y * 128;
  const long bn = (long)blockIdx.x * 128;

  const int srow = lane >> 3;          // row within 8-row chunk
  const int skc = (lane & 7) ^ srow;   // swizzled k-chunk this lane fetches

  const u16* Ag = A + (bm + wave * 32 + srow) * (long)K + skc * 8;
  const u16* Bg = Bt + (bn + wave * 32 + srow) * (long)K + skc * 8;

  f32x4 acc[4][4] = {};

  for (int kt = 0; kt < K; kt += 64) {
#pragma unroll
    for (int i = 0; i < 4; ++i) {
      gl_lds16(Ag + (long)i * 8 * K + kt, &As[(wave * 4 + i) * 512]);
      gl_lds16(Bg + (long)i * 8 * K + kt, &Bs[(wave * 4 + i) * 512]);
    }
    __syncthreads();
#pragma unroll
    for (int h2 = 0; h2 < 2; ++h2) {
      const int kc = h2 * 4 + (lane >> 4);
      const int swz = (kc ^ (lane & 7)) * 8;  // (m&7) == (lane&7) for frag rows
      bf16x8 af[4], bfr[4];
#pragma unroll
      for (int i = 0; i < 4; ++i) {
        const int m = wm * 64 + i * 16 + (lane & 15);
        af[i] = *(const bf16x8*)&As[m * 64 + swz];
        const int n = wn * 64 + i * 16 + (lane & 15);
        bfr[i] = *(const bf16x8*)&Bs[n * 64 + swz];
      }
#pragma unroll
      for (int i = 0; i < 4; ++i)
#pragma unroll
        for (int j = 0; j < 4; ++j)
          acc[i][j] = __builtin_amdgcn_mfma_f32_16x16x32_bf16(af[i], bfr[j], acc[i][j], 0, 0, 0);
    }
    __syncthreads();
  }

  // Epilogue. C/D layout: col = lane&15, row = (lane>>4)*4 + reg  [verified m89/m91]
  if constexpr (EPI == 0) {
    u16* dst = (u16*)dstv;
#pragma unroll
    for (int i = 0; i < 4; ++i)
#pragma unroll
      for (int r = 0; r < 4; ++r) {
        const long row = bm + wm * 64 + i * 16 + (lane >> 4) * 4 + r;
#pragma unroll
        for (int j = 0; j < 4; ++j) {
          const long col = bn + wn * 64 + j * 16 + (lane & 15);
          float v = acc[i][j][r] + bias[col];
          float g = 0.5f * v * (1.0f + erff(v * 0.70710678118654752f));
          dst[row * N + col] = f2bf(g);
        }
      }
  } else if constexpr (EPI == 1) {
    u16* dst = (u16*)dstv;  // merged, ld 4096
#pragma unroll
    for (int i = 0; i < 4; ++i)
#pragma unroll
      for (int r = 0; r < 4; ++r) {
        const long row = bm + wm * 64 + i * 16 + (lane >> 4) * 4 + r;
        const float4 rv = *(const float4*)(scal + row * 8);
        const float4 hv = *(const float4*)(scal + row * 8 + 4);
#pragma unroll
        for (int j = 0; j < 4; ++j) {
          const long col = bn + wn * 64 + j * 16 + (lane & 15);
          const float f = acc[i][j][r] + bias[col];
          const float xval = X[row * 1024 + col];
          const long base = row * 4096 + col;
          dst[base] = f2bf(rv.x * xval + hv.x * f);
          dst[base + 1024] = f2bf(rv.y * xval + hv.y * f);
          dst[base + 2048] = f2bf(rv.z * xval + hv.z * f);
          dst[base + 3072] = f2bf(rv.w * xval + hv.w * f);
        }
      }
  } else {
    float* dst = (float*)dstv;
#pragma unroll
    for (int i = 0; i < 4; ++i)
#pragma unroll
      for (int r = 0; r < 4; ++r) {
        const long row = bm + wm * 64 + i * 16 + (lane >> 4) * 4 + r;
#pragma unroll
        for (int j = 0; j < 4; ++j) {
          const long col = bn + wn * 64 + j * 16 + (lane & 15);
          dst[row * 1024 + col] = acc[i][j][r] + bias[col] + X[row * 1024 + col];
        }
      }
  }
}

extern "C" void kernel_launch(void* const* d_in, const int* in_sizes, int n_in,
                              void* d_out, int out_size, void* d_ws, size_t ws_size,
                              hipStream_t stream) {
  (void)in_sizes; (void)n_in; (void)out_size; (void)ws_size;
  const float* x = (const float*)d_in[0];
  const float* rmsw = (const float*)d_in[1];
  const float* Wdyn = (const float*)d_in[2];
  const float* bias_pre = (const float*)d_in[3];
  const float* bias_post = (const float*)d_in[4];
  const float* bias_res = (const float*)d_in[5];
  const float* a_pre = (const float*)d_in[6];
  const float* a_post = (const float*)d_in[7];
  const float* a_res = (const float*)d_in[8];
  const float* W1 = (const float*)d_in[9];
  const float* b1 = (const float*)d_in[10];
  const float* W2 = (const float*)d_in[11];
  const float* b2 = (const float*)d_in[12];
  const float* Wout = (const float*)d_in[13];
  const float* bout = (const float*)d_in[14];
  float* out = (float*)d_out;
  char* ws = (char*)d_ws;

  // workspace layout (bytes); merged overlaps preA (preA dead after GEMM1)
  constexpr size_t OFF_W1BT = 0;          // 4096x1024 bf16  (8 MiB)
  constexpr size_t OFF_W2BT = 8388608;    // 1024x4096 bf16  (8 MiB)
  constexpr size_t OFF_WOBT = 16777216;   // 1024x4096 bf16  (8 MiB)
  constexpr size_t OFF_WEFF = 25165824;   // 1024x24 f32     (96 KiB)
  constexpr size_t OFF_SCAL = 25264128;   // 8192x8 f32      (256 KiB)
  constexpr size_t OFF_H    = 25526272;   // 8192x4096 bf16  (64 MiB)
  constexpr size_t OFF_PREA = 92635136;   // 8192x1024 bf16  (16 MiB)
  constexpr size_t OFF_MERG = 92635136;   // 8192x4096 bf16  (64 MiB) -- total 159,744,000 B

  u16* W1bt = (u16*)(ws + OFF_W1BT);
  u16* W2bt = (u16*)(ws + OFF_W2BT);
  u16* Wobt = (u16*)(ws + OFF_WOBT);
  float* Weff = (float*)(ws + OFF_WEFF);
  float* scal = (float*)(ws + OFF_SCAL);
  u16* h = (u16*)(ws + OFF_H);
  u16* preA = (u16*)(ws + OFF_PREA);
  u16* merged = (u16*)(ws + OFF_MERG);

  weff_kernel<<<96, 256, 0, stream>>>(rmsw, Wdyn, Weff);
  transpose_kernel<<<dim3(128, 32), 256, 0, stream>>>(W1, W1bt, 1024, 4096);
  transpose_kernel<<<dim3(32, 128), 256, 0, stream>>>(W2, W2bt, 4096, 1024);
  transpose_kernel<<<dim3(32, 128), 256, 0, stream>>>(Wout, Wobt, 4096, 1024);
  prep_tokens<<<8192, 256, 0, stream>>>(x, Weff, bias_pre, bias_post, bias_res,
                                        a_pre, a_post, a_res, preA, scal);
  // h = gelu(preA @ W1 + b1)                      M=8192 N=4096 K=1024
  gemm_bf16<0><<<dim3(32, 64), 256, 0, stream>>>(preA, W1bt, 1024, 4096, b1, nullptr, nullptr, h);
  // merged[:, s*1024+c] = r_s*x + hp_s*(h @ W2 + b2)   M=8192 N=1024 K=4096
  gemm_bf16<1><<<dim3(8, 64), 256, 0, stream>>>(h, W2bt, 4096, 1024, b2, x, scal, merged);
  // out = merged @ Wout + bout + x                M=8192 N=1024 K=4096
  gemm_bf16<2><<<dim3(8, 64), 256, 0, stream>>>(merged, Wobt, 4096, 1024, bout, x, nullptr, out);
}

// Round 2
// 582.839 us; speedup vs baseline: 1.0110x; 1.0110x over previous
//
#include <hip/hip_runtime.h>

typedef unsigned short u16;
typedef __bf16 bf16x8 __attribute__((ext_vector_type(8)));
typedef float f32x4 __attribute__((ext_vector_type(4)));

typedef __attribute__((address_space(1))) void gvoid;
typedef __attribute__((address_space(3))) void lvoid;

__device__ __forceinline__ u16 f2bf(float f) {
  unsigned int u = __builtin_bit_cast(unsigned int, f);
  u += 0x7fffu + ((u >> 16) & 1u);
  return (u16)(u >> 16);
}

__device__ __forceinline__ void gl_lds16(const u16* g, u16* l) {
  // async global->LDS, 16B per lane; LDS dest = wave-uniform base + lane*16
  __builtin_amdgcn_global_load_lds((gvoid*)(g), (lvoid*)(l), 16, 0, 0);
}

// ---------------- W_eff[c][j] = sum_s rmsw[s*1024+c] * Wdyn[(s*1024+c)*24 + j] ---------
__global__ __launch_bounds__(256) void weff_kernel(const float* __restrict__ rmsw,
                                                   const float* __restrict__ Wdyn,
                                                   float* __restrict__ Weff) {
  int idx = blockIdx.x * 256 + threadIdx.x;  // 1024*24 = 24576 threads
  int c = idx / 24, j = idx - c * 24;
  float s = 0.f;
#pragma unroll
  for (int st = 0; st < 4; ++st) {
    int r = st * 1024 + c;
    s += rmsw[r] * Wdyn[(long)r * 24 + j];
  }
  Weff[idx] = s;
}

// ---------------- transpose fp32 (R x C) -> bf16 (C x R) --------------------------------
__global__ __launch_bounds__(256) void transpose_kernel(const float* __restrict__ src,
                                                        u16* __restrict__ dst,
                                                        int R, int C) {
  __shared__ float tile[32][33];
  int tx = threadIdx.x & 31, ty = threadIdx.x >> 5;  // 32 x 8
  long c0 = (long)blockIdx.x * 32, r0 = (long)blockIdx.y * 32;
#pragma unroll
  for (int k = 0; k < 4; ++k)
    tile[ty + 8 * k][tx] = src[(r0 + ty + 8 * k) * C + c0 + tx];
  __syncthreads();
#pragma unroll
  for (int k = 0; k < 4; ++k)
    dst[(c0 + ty + 8 * k) * R + r0 + tx] = f2bf(tile[tx][ty + 8 * k]);
}

// ---------------- per-token prep: rms, dynamic(24), gates, sinkhorn, preA ---------------
__global__ __launch_bounds__(256) void prep_tokens(
    const float* __restrict__ x, const float* __restrict__ Weff,
    const float* __restrict__ bias_pre, const float* __restrict__ bias_post,
    const float* __restrict__ bias_res, const float* __restrict__ a_pre,
    const float* __restrict__ a_post, const float* __restrict__ a_res,
    u16* __restrict__ preA, float* __restrict__ scal) {
  const int t = blockIdx.x;
  const int tid = threadIdx.x;
  const float4 xv = *(const float4*)(x + (long)t * 1024 + tid * 4);
  float ssq = xv.x * xv.x + xv.y * xv.y + xv.z * xv.z + xv.w * xv.w;
  float raw[24];
#pragma unroll
  for (int j = 0; j < 24; ++j) raw[j] = 0.f;
  const float xs[4] = {xv.x, xv.y, xv.z, xv.w};
  const float* wrow = Weff + (long)tid * 96;  // 4 rows of 24
#pragma unroll
  for (int cc = 0; cc < 4; ++cc) {
    const float4* wr = (const float4*)(wrow + cc * 24);
    const float xc = xs[cc];
#pragma unroll
    for (int q = 0; q < 6; ++q) {
      float4 w = wr[q];
      raw[q * 4 + 0] += xc * w.x;
      raw[q * 4 + 1] += xc * w.y;
      raw[q * 4 + 2] += xc * w.z;
      raw[q * 4 + 3] += xc * w.w;
    }
  }
  // wave64 butterfly reduce of 25 partials
#pragma unroll
  for (int m = 1; m < 64; m <<= 1) {
    ssq += __shfl_xor(ssq, m);
#pragma unroll
    for (int j = 0; j < 24; ++j) raw[j] += __shfl_xor(raw[j], m);
  }
  __shared__ float red[4][25];
  __shared__ float tot[25];
  const int lane = tid & 63, wv = tid >> 6;
  if (lane == 0) {
#pragma unroll
    for (int j = 0; j < 24; ++j) red[wv][j] = raw[j];
    red[wv][24] = ssq;
  }
  __syncthreads();
  if (tid < 25) tot[tid] = red[0][tid] + red[1][tid] + red[2][tid] + red[3][tid];
  __syncthreads();

  const float rms = sqrtf(tot[24] * (1.0f / 1024.0f) + 1e-8f);
  const float rinv = 1.0f / rms;

  // s_pre (every thread computes; identical)
  const float ap = a_pre[0];
  float s_pre = 0.f;
#pragma unroll
  for (int i = 0; i < 4; ++i)
    s_pre += 1.f / (1.f + expf(-(ap * tot[i] * rinv + bias_pre[i])));

  // preA = bf16(s_pre * x)
  unsigned int lo = (unsigned)f2bf(s_pre * xv.x) | ((unsigned)f2bf(s_pre * xv.y) << 16);
  unsigned int hi = (unsigned)f2bf(s_pre * xv.z) | ((unsigned)f2bf(s_pre * xv.w) << 16);
  *(uint2*)(preA + (long)t * 1024 + tid * 4) = make_uint2(lo, hi);

  // sinkhorn on lanes 0..15 of wave 0 (lane = i*4 + j)
  if (tid < 16) {
    const float ar = a_res[0];
    float Mv = expf(ar * tot[8 + tid] * rinv + bias_res[tid]);
#pragma unroll
    for (int it = 0; it < 20; ++it) {
      float cs = Mv + __shfl_xor(Mv, 4);
      cs += __shfl_xor(cs, 8);
      Mv = Mv / (cs + 1e-8f);   // col normalize (axis=-2)
      float rs = Mv + __shfl_xor(Mv, 1);
      rs += __shfl_xor(rs, 2);
      Mv = Mv / (rs + 1e-8f);   // row normalize (axis=-1)
    }
    float rs = Mv + __shfl_xor(Mv, 1);
    rs += __shfl_xor(rs, 2);
    if ((tid & 3) == 0) scal[(long)t * 8 + (tid >> 2)] = rs;  // r_i
  }
  if (tid < 4) {
    const float apo = a_post[0];
    float hp = 2.f / (1.f + expf(-(apo * tot[4 + tid] * rinv + bias_post[tid])));
    scal[(long)t * 8 + 4 + tid] = hp;  // H_post
  }
}

// ---------------- bf16 MFMA GEMM: C(MxN) = A(MxK, row-major) * Bt(NxK)^T ----------------
// BM=BN=128, BK=64, 256 threads (4 waves, 2x2), each wave 4x4 of 16x16x32 MFMA.
// Double-buffered LDS + single barrier per K-tile: prefetch tile kt+1 via
// global_load_lds into buf p^1 while computing tile kt from buf p. The
// compiler's vmcnt(0)-before-barrier drain then lands AFTER a full compute
// phase, hiding the global->LDS latency (the round-1 kernel exposed it).
// LDS layout XOR-swizzled: elem (m, kc) at phys m*64 + ((kc ^ (m&7))*8)  [kc = k/8]
//  -> global_load_lds-compatible (contiguous lane order), conflict-free ds_read_b128,
//     coalesced 128B-per-8-lane global reads.
// EPI: 0 = gelu -> bf16 dst (ld N) | 1 = build merged (ld 4096) | 2 = +bias+x -> fp32
template <int EPI>
__global__ __launch_bounds__(256) void gemm_bf16(const u16* __restrict__ A,
                                                 const u16* __restrict__ Bt,
                                                 const int K, const int N,
                                                 const float* __restrict__ bias,
                                                 const float* __restrict__ X,
                                                 const float* __restrict__ scal,
                                                 void* __restrict__ dstv) {
  __shared__ __attribute__((aligned(16))) u16 As[2][128 * 64];
  __shared__ __attribute__((aligned(16))) u16 Bs[2][128 * 64];
  const int tid = threadIdx.x;
  const int lane = tid & 63;
  const int wave = tid >> 6;
  const int wm = wave >> 1, wn = wave & 1;
  const long bm = (long)blockIdx.y * 128;
  const long bn = (long)blockIdx.x * 128;

  const int srow = lane >> 3;          // row within 8-row chunk
  const int skc = (lane & 7) ^ srow;   // swizzled k-chunk this lane fetches

  const u16* Ag = A + (bm + wave * 32 + srow) * (long)K + skc * 8;
  const u16* Bg = Bt + (bn + wave * 32 + srow) * (long)K + skc * 8;

  f32x4 acc[4][4] = {};

  const int T = K >> 6;  // K-tiles of 64

  // prologue: stage tile 0 into buffer 0
#pragma unroll
  for (int i = 0; i < 4; ++i) {
    gl_lds16(Ag + (long)i * 8 * K, &As[0][(wave * 4 + i) * 512]);
    gl_lds16(Bg + (long)i * 8 * K, &Bs[0][(wave * 4 + i) * 512]);
  }

  for (int kt = 0; kt < T; ++kt) {
    const int p = kt & 1;
    __syncthreads();  // drains vmcnt -> buf p ready; buf p^1 reads (prev iter) retired
    if (kt + 1 < T) {
      const long ko = (long)(kt + 1) * 64;
#pragma unroll
      for (int i = 0; i < 4; ++i) {
        gl_lds16(Ag + (long)i * 8 * K + ko, &As[p ^ 1][(wave * 4 + i) * 512]);
        gl_lds16(Bg + (long)i * 8 * K + ko, &Bs[p ^ 1][(wave * 4 + i) * 512]);
      }
    }
#pragma unroll
    for (int h2 = 0; h2 < 2; ++h2) {
      const int kc = h2 * 4 + (lane >> 4);
      const int swz = (kc ^ (lane & 7)) * 8;  // (m&7) == (lane&7) for frag rows
      bf16x8 af[4], bfr[4];
#pragma unroll
      for (int i = 0; i < 4; ++i) {
        const int m = wm * 64 + i * 16 + (lane & 15);
        af[i] = *(const bf16x8*)&As[p][m * 64 + swz];
        const int n = wn * 64 + i * 16 + (lane & 15);
        bfr[i] = *(const bf16x8*)&Bs[p][n * 64 + swz];
      }
#pragma unroll
      for (int i = 0; i < 4; ++i)
#pragma unroll
        for (int j = 0; j < 4; ++j)
          acc[i][j] = __builtin_amdgcn_mfma_f32_16x16x32_bf16(af[i], bfr[j], acc[i][j], 0, 0, 0);
    }
  }

  // Epilogue. C/D layout: col = lane&15, row = (lane>>4)*4 + reg  [verified m89/m91]
  if constexpr (EPI == 0) {
    u16* dst = (u16*)dstv;
#pragma unroll
    for (int i = 0; i < 4; ++i)
#pragma unroll
      for (int r = 0; r < 4; ++r) {
        const long row = bm + wm * 64 + i * 16 + (lane >> 4) * 4 + r;
#pragma unroll
        for (int j = 0; j < 4; ++j) {
          const long col = bn + wn * 64 + j * 16 + (lane & 15);
          float v = acc[i][j][r] + bias[col];
          float g = 0.5f * v * (1.0f + erff(v * 0.70710678118654752f));
          dst[row * N + col] = f2bf(g);
        }
      }
  } else if constexpr (EPI == 1) {
    u16* dst = (u16*)dstv;  // merged, ld 4096
#pragma unroll
    for (int i = 0; i < 4; ++i)
#pragma unroll
      for (int r = 0; r < 4; ++r) {
        const long row = bm + wm * 64 + i * 16 + (lane >> 4) * 4 + r;
        const float4 rv = *(const float4*)(scal + row * 8);
        const float4 hv = *(const float4*)(scal + row * 8 + 4);
#pragma unroll
        for (int j = 0; j < 4; ++j) {
          const long col = bn + wn * 64 + j * 16 + (lane & 15);
          const float f = acc[i][j][r] + bias[col];
          const float xval = X[row * 1024 + col];
          const long base = row * 4096 + col;
          dst[base] = f2bf(rv.x * xval + hv.x * f);
          dst[base + 1024] = f2bf(rv.y * xval + hv.y * f);
          dst[base + 2048] = f2bf(rv.z * xval + hv.z * f);
          dst[base + 3072] = f2bf(rv.w * xval + hv.w * f);
        }
      }
  } else {
    float* dst = (float*)dstv;
#pragma unroll
    for (int i = 0; i < 4; ++i)
#pragma unroll
      for (int r = 0; r < 4; ++r) {
        const long row = bm + wm * 64 + i * 16 + (lane >> 4) * 4 + r;
#pragma unroll
        for (int j = 0; j < 4; ++j) {
          const long col = bn + wn * 64 + j * 16 + (lane & 15);
          dst[row * 1024 + col] = acc[i][j][r] + bias[col] + X[row * 1024 + col];
        }
      }
  }
}

extern "C" void kernel_launch(void* const* d_in, const int* in_sizes, int n_in,
                              void* d_out, int out_size, void* d_ws, size_t ws_size,
                              hipStream_t stream) {
  (void)in_sizes; (void)n_in; (void)out_size; (void)ws_size;
  const float* x = (const float*)d_in[0];
  const float* rmsw = (const float*)d_in[1];
  const float* Wdyn = (const float*)d_in[2];
  const float* bias_pre = (const float*)d_in[3];
  const float* bias_post = (const float*)d_in[4];
  const float* bias_res = (const float*)d_in[5];
  const float* a_pre = (const float*)d_in[6];
  const float* a_post = (const float*)d_in[7];
  const float* a_res = (const float*)d_in[8];
  const float* W1 = (const float*)d_in[9];
  const float* b1 = (const float*)d_in[10];
  const float* W2 = (const float*)d_in[11];
  const float* b2 = (const float*)d_in[12];
  const float* Wout = (const float*)d_in[13];
  const float* bout = (const float*)d_in[14];
  float* out = (float*)d_out;
  char* ws = (char*)d_ws;

  // workspace layout (bytes); merged overlaps preA (preA dead after GEMM1)
  constexpr size_t OFF_W1BT = 0;          // 4096x1024 bf16  (8 MiB)
  constexpr size_t OFF_W2BT = 8388608;    // 1024x4096 bf16  (8 MiB)
  constexpr size_t OFF_WOBT = 16777216;   // 1024x4096 bf16  (8 MiB)
  constexpr size_t OFF_WEFF = 25165824;   // 1024x24 f32     (96 KiB)
  constexpr size_t OFF_SCAL = 25264128;   // 8192x8 f32      (256 KiB)
  constexpr size_t OFF_H    = 25526272;   // 8192x4096 bf16  (64 MiB)
  constexpr size_t OFF_PREA = 92635136;   // 8192x1024 bf16  (16 MiB)
  constexpr size_t OFF_MERG = 92635136;   // 8192x4096 bf16  (64 MiB) -- total 159,744,000 B

  u16* W1bt = (u16*)(ws + OFF_W1BT);
  u16* W2bt = (u16*)(ws + OFF_W2BT);
  u16* Wobt = (u16*)(ws + OFF_WOBT);
  float* Weff = (float*)(ws + OFF_WEFF);
  float* scal = (float*)(ws + OFF_SCAL);
  u16* h = (u16*)(ws + OFF_H);
  u16* preA = (u16*)(ws + OFF_PREA);
  u16* merged = (u16*)(ws + OFF_MERG);

  weff_kernel<<<96, 256, 0, stream>>>(rmsw, Wdyn, Weff);
  transpose_kernel<<<dim3(128, 32), 256, 0, stream>>>(W1, W1bt, 1024, 4096);
  transpose_kernel<<<dim3(32, 128), 256, 0, stream>>>(W2, W2bt, 4096, 1024);
  transpose_kernel<<<dim3(32, 128), 256, 0, stream>>>(Wout, Wobt, 4096, 1024);
  prep_tokens<<<8192, 256, 0, stream>>>(x, Weff, bias_pre, bias_post, bias_res,
                                        a_pre, a_post, a_res, preA, scal);
  // h = gelu(preA @ W1 + b1)                      M=8192 N=4096 K=1024
  gemm_bf16<0><<<dim3(32, 64), 256, 0, stream>>>(preA, W1bt, 1024, 4096, b1, nullptr, nullptr, h);
  // merged[:, s*1024+c] = r_s*x + hp_s*(h @ W2 + b2)   M=8192 N=1024 K=4096
  gemm_bf16<1><<<dim3(8, 64), 256, 0, stream>>>(h, W2bt, 4096, 1024, b2, x, scal, merged);
  // out = merged @ Wout + bout + x                M=8192 N=1024 K=4096
  gemm_bf16<2><<<dim3(8, 64), 256, 0, stream>>>(merged, Wobt, 4096, 1024, bout, x, nullptr, out);
}